// Round 1
// baseline (1894.154 us; speedup 1.0000x reference)
//
#include <hip/hip_runtime.h>

#define MDIM 1024
#define FFH  2048
#define SEQ  2048
#define NROWS 4096
#define NEGV -1e9f

typedef __attribute__((ext_vector_type(8))) __bf16 bf16x8;
typedef __attribute__((ext_vector_type(4))) float floatx4;

__device__ __forceinline__ unsigned short f2bf(float f){
  union { float f; unsigned u; } v; v.f = f;
  unsigned u = v.u;
  u += 0x7fffu + ((u >> 16) & 1u);
  return (unsigned short)(u >> 16);
}

// ---------------- prep kernels ----------------
__global__ void k_cvt_bf16(const float* __restrict__ src, unsigned short* __restrict__ dst){
  int i = (blockIdx.x * 256 + threadIdx.x) * 4;
  float4 v = *(const float4*)(src + i);
  ushort4 o;
  o.x = f2bf(v.x); o.y = f2bf(v.y); o.z = f2bf(v.z); o.w = f2bf(v.w);
  *(ushort4*)(dst + i) = o;
}

// Wq/Wk/Wv [16][1024][64] -> fused B^T layout [3072][1024]: dst[n][m] = W{t}[h][m][d], n = t*1024 + h*64 + d
__global__ void k_build_wqkvt(const float* __restrict__ Wq, const float* __restrict__ Wk,
                              const float* __restrict__ Wv, unsigned short* __restrict__ dst){
  int i = blockIdx.x * 256 + threadIdx.x;   // over 3072*1024
  int m  = i & 1023;
  int nr = i >> 10;                          // 0..3071
  const float* W = (nr < 1024) ? Wq : (nr < 2048) ? Wk : Wv;
  int hd = nr & 1023;
  dst[i] = f2bf(W[((size_t)(hd >> 6) << 16) + ((size_t)m << 6) + (hd & 63)]);
}

__global__ void k_build_qbias(const float* __restrict__ bq, const float* __restrict__ bk,
                              const float* __restrict__ bv, float* __restrict__ dst){
  int i = blockIdx.x * 256 + threadIdx.x;   // 3072
  dst[i] = (i < 1024) ? bq[i] : (i < 2048) ? bk[i - 1024] : bv[i - 2048];
}

// src [K][N] fp32 -> dst [N][K] bf16 (B^T layout), K = 1<<kshift
__global__ void k_transpose(const float* __restrict__ src, unsigned short* __restrict__ dst,
                            int kshift, int N){
  int i = blockIdx.x * 256 + threadIdx.x;   // over N*K
  int K = 1 << kshift;
  int k = i & (K - 1);
  int n = i >> kshift;
  dst[i] = f2bf(src[(size_t)k * N + n]);
}

// ---------------- bf16 MFMA GEMM: C[M][N] = A[M][K] @ Bt[N][K]^T + bias ----------------
// 64x64 tile per block (256 threads, 4 waves; wave w owns rows w*16..w*16+15).
template<int RELU, int OUTBF>
__global__ void __launch_bounds__(256) k_gemm(const unsigned short* __restrict__ A,
                                              const unsigned short* __restrict__ Bt,
                                              const float* __restrict__ bias,
                                              void* __restrict__ Cout, int N, int K){
  __shared__ unsigned short As[64 * 32];
  __shared__ unsigned short Bs[64 * 32];
  const int t = threadIdx.x;
  const int m0 = blockIdx.y << 6, n0 = blockIdx.x << 6;
  const int lane = t & 63, w = t >> 6;
  const int quad = lane >> 4, l16 = lane & 15;
  const int sr = t >> 2, sc = (t & 3) << 3;   // staging: row 0..63, col {0,8,16,24}
  floatx4 acc[4];
  #pragma unroll
  for (int i = 0; i < 4; i++) acc[i] = (floatx4){0.f, 0.f, 0.f, 0.f};
  const unsigned short* Ag = A  + (size_t)(m0 + sr) * K + sc;
  const unsigned short* Bg = Bt + (size_t)(n0 + sr) * K + sc;
  for (int kb = 0; kb < K; kb += 32){
    uint4 av = *(const uint4*)(Ag + kb);
    uint4 bv = *(const uint4*)(Bg + kb);
    *(uint4*)&As[(sr << 5) + sc] = av;
    *(uint4*)&Bs[(sr << 5) + sc] = bv;
    __syncthreads();
    // A frag: A[m = lane&15][k = quad*8+j]  (rows w*16 + l16)
    bf16x8 af = *(const bf16x8*)&As[(((w << 4) + l16) << 5) + (quad << 3)];
    #pragma unroll
    for (int ns = 0; ns < 4; ns++){
      bf16x8 bfr = *(const bf16x8*)&Bs[(((ns << 4) + l16) << 5) + (quad << 3)];
      acc[ns] = __builtin_amdgcn_mfma_f32_16x16x32_bf16(af, bfr, acc[ns], 0, 0, 0);
    }
    __syncthreads();
  }
  // C/D layout: col = lane&15, row = quad*4 + reg   [measured m89/m91]
  #pragma unroll
  for (int ns = 0; ns < 4; ns++){
    const int col = n0 + (ns << 4) + l16;
    const float bsv = bias[col];
    #pragma unroll
    for (int r = 0; r < 4; r++){
      const int row = m0 + (w << 4) + (quad << 2) + r;
      float v = acc[ns][r] + bsv;
      if (RELU) v = fmaxf(v, 0.f);
      if (OUTBF) ((unsigned short*)Cout)[(size_t)row * N + col] = f2bf(v);
      else       ((float*)Cout)[(size_t)row * N + col] = v;
    }
  }
}

// ---------------- flash attention (fp32), one block per (b,h,q-tile of 64) ----------------
// thread t: q-row r = t>>2, key-group g = t&3 handles local keys {j*4+g}.
// LDS row stride 72 floats: K/V float4 reads land on banks 8g..8g+3 -> conflict-free.
__global__ void __launch_bounds__(256) k_attn(const float* __restrict__ qkv,
                                              const int* __restrict__ amask,
                                              unsigned short* __restrict__ ctxb){
  __shared__ __align__(16) float Qs[64 * 72];
  __shared__ __align__(16) float Ks[64 * 72];
  __shared__ __align__(16) float Vs[64 * 72];
  __shared__ int msk[64];
  const int t = threadIdx.x;
  const int b = blockIdx.y >> 4, h = blockIdx.y & 15;
  const int q0 = blockIdx.x << 6;
  const int r = t >> 2, g = t & 3;
  const int lc = g << 4;
  {
    const float4* src = (const float4*)(qkv + (size_t)((b << 11) + q0 + r) * 3072 + (h << 6) + lc);
    float4* dst = (float4*)&Qs[r * 72 + lc];
    #pragma unroll
    for (int i = 0; i < 4; i++) dst[i] = src[i];
  }
  float4 O4[16];
  #pragma unroll
  for (int i = 0; i < 16; i++) O4[i] = make_float4(0.f, 0.f, 0.f, 0.f);
  float run_m = -3.0e38f, run_l = 0.f;

  for (int k0 = 0; k0 < SEQ; k0 += 64){
    __syncthreads();   // protects Q (iter 0) and Ks/Vs from previous iteration's readers
    {
      const float4* ksrc = (const float4*)(qkv + (size_t)((b << 11) + k0 + r) * 3072 + 1024 + (h << 6) + lc);
      const float4* vsrc = (const float4*)(qkv + (size_t)((b << 11) + k0 + r) * 3072 + 2048 + (h << 6) + lc);
      float4* kdst = (float4*)&Ks[r * 72 + lc];
      float4* vdst = (float4*)&Vs[r * 72 + lc];
      #pragma unroll
      for (int i = 0; i < 4; i++){ kdst[i] = ksrc[i]; vdst[i] = vsrc[i]; }
      if (t < 64) msk[t] = amask[(b << 11) + k0 + t];
    }
    __syncthreads();
    float s[16];
    #pragma unroll
    for (int j = 0; j < 16; j++) s[j] = 0.f;
    #pragma unroll 4
    for (int i = 0; i < 16; i++){
      const float4 q4 = ((const float4*)Qs)[r * 18 + i];
      #pragma unroll
      for (int j = 0; j < 16; j++){
        const float4 k4 = ((const float4*)Ks)[((j << 2) + g) * 18 + i];
        s[j] += q4.x * k4.x + q4.y * k4.y + q4.z * k4.z + q4.w * k4.w;
      }
    }
    float tm = -3.0e38f;
    #pragma unroll
    for (int j = 0; j < 16; j++){
      s[j] *= 0.125f;                       // 1/sqrt(64)
      if (msk[(j << 2) + g] == 0) s[j] = NEGV;
      tm = fmaxf(tm, s[j]);
    }
    tm = fmaxf(tm, __shfl_xor(tm, 1));
    tm = fmaxf(tm, __shfl_xor(tm, 2));
    const float nm = fmaxf(run_m, tm);
    const float alpha = __expf(run_m - nm);
    float ts = 0.f;
    #pragma unroll
    for (int j = 0; j < 16; j++){ s[j] = __expf(s[j] - nm); ts += s[j]; }
    ts += __shfl_xor(ts, 1);
    ts += __shfl_xor(ts, 2);
    run_l = run_l * alpha + ts;
    run_m = nm;
    #pragma unroll
    for (int i = 0; i < 16; i++){
      O4[i].x *= alpha; O4[i].y *= alpha; O4[i].z *= alpha; O4[i].w *= alpha;
    }
    #pragma unroll
    for (int j = 0; j < 16; j++){
      const float p = s[j];
      const float4* Vr = (const float4*)&Vs[((j << 2) + g) * 72];
      #pragma unroll
      for (int i = 0; i < 16; i++){
        O4[i].x += p * Vr[i].x; O4[i].y += p * Vr[i].y;
        O4[i].z += p * Vr[i].z; O4[i].w += p * Vr[i].w;
      }
    }
  }
  // combine the 4 per-group partials (butterfly within wave: lanes l, l^1, l^2 share q-row)
  #pragma unroll
  for (int i = 0; i < 16; i++){
    O4[i].x += __shfl_xor(O4[i].x, 1); O4[i].y += __shfl_xor(O4[i].y, 1);
    O4[i].z += __shfl_xor(O4[i].z, 1); O4[i].w += __shfl_xor(O4[i].w, 1);
    O4[i].x += __shfl_xor(O4[i].x, 2); O4[i].y += __shfl_xor(O4[i].y, 2);
    O4[i].z += __shfl_xor(O4[i].z, 2); O4[i].w += __shfl_xor(O4[i].w, 2);
  }
  const float inv = 1.f / run_l;
  unsigned short* dst = ctxb + (size_t)((b << 11) + q0 + r) * 1024 + (h << 6);
  #pragma unroll
  for (int i = 0; i < 4; i++){
    const int ii = (g << 2) + i;
    dst[(ii << 2) + 0] = f2bf(O4[ii].x * inv);
    dst[(ii << 2) + 1] = f2bf(O4[ii].y * inv);
    dst[(ii << 2) + 2] = f2bf(O4[ii].z * inv);
    dst[(ii << 2) + 3] = f2bf(O4[ii].w * inv);
  }
}

// ---------------- residual + LayerNorm (1024 cols, one block per row) ----------------
__global__ void __launch_bounds__(256) k_ln(const float* __restrict__ a, const float* __restrict__ res,
                                            const float* __restrict__ gg, const float* __restrict__ bb,
                                            float* __restrict__ out, unsigned short* __restrict__ outb){
  const int row = blockIdx.x, t = threadIdx.x;
  const float4 av = ((const float4*)(a   + (size_t)row * 1024))[t];
  const float4 rv = ((const float4*)(res + (size_t)row * 1024))[t];
  float4 v; v.x = av.x + rv.x; v.y = av.y + rv.y; v.z = av.z + rv.z; v.w = av.w + rv.w;
  float sum = v.x + v.y + v.z + v.w;
  float ss  = v.x * v.x + v.y * v.y + v.z * v.z + v.w * v.w;
  #pragma unroll
  for (int off = 32; off > 0; off >>= 1){
    sum += __shfl_down(sum, off);
    ss  += __shfl_down(ss, off);
  }
  __shared__ float red[8];
  const int w = t >> 6;
  if ((t & 63) == 0){ red[w] = sum; red[4 + w] = ss; }
  __syncthreads();
  const float S  = red[0] + red[1] + red[2] + red[3];
  const float SS = red[4] + red[5] + red[6] + red[7];
  const float mu  = S * (1.f / 1024.f);
  const float var = SS * (1.f / 1024.f) - mu * mu;
  const float rs  = rsqrtf(var + 1e-5f);
  const float4 gv = ((const float4*)gg)[t];
  const float4 bv = ((const float4*)bb)[t];
  float4 o;
  o.x = (v.x - mu) * rs * gv.x + bv.x;
  o.y = (v.y - mu) * rs * gv.y + bv.y;
  o.z = (v.z - mu) * rs * gv.z + bv.z;
  o.w = (v.w - mu) * rs * gv.w + bv.w;
  ((float4*)(out + (size_t)row * 1024))[t] = o;
  if (outb){
    ushort4 ob; ob.x = f2bf(o.x); ob.y = f2bf(o.y); ob.z = f2bf(o.z); ob.w = f2bf(o.w);
    ((ushort4*)(outb + (size_t)row * 1024))[t] = ob;
  }
}

extern "C" void kernel_launch(void* const* d_in, const int* in_sizes, int n_in,
                              void* d_out, int out_size, void* d_ws, size_t ws_size,
                              hipStream_t stream){
  const float* x     = (const float*)d_in[0];
  const int*   amask = (const int*)d_in[1];
  const float* Wq    = (const float*)d_in[2];
  const float* bq    = (const float*)d_in[3];
  const float* Wk    = (const float*)d_in[4];
  const float* bk    = (const float*)d_in[5];
  const float* Wv    = (const float*)d_in[6];
  const float* bv    = (const float*)d_in[7];
  const float* Wo    = (const float*)d_in[8];
  const float* bo    = (const float*)d_in[9];
  const float* g1    = (const float*)d_in[10];
  const float* b1    = (const float*)d_in[11];
  const float* W1    = (const float*)d_in[12];
  const float* bias1 = (const float*)d_in[13];
  const float* W2    = (const float*)d_in[14];
  const float* bias2 = (const float*)d_in[15];
  const float* g2    = (const float*)d_in[16];
  const float* b2    = (const float*)d_in[17];

  char* ws = (char*)d_ws;
  unsigned short* xb    = (unsigned short*)(ws + 0);            //  8 MB: x as bf16
  unsigned short* wqkvt = (unsigned short*)(ws + 8388608);      //  6 MB: fused QKV weights, B^T layout
  float*          qbias = (float*)         (ws + 14680064);     // 12 KB
  unsigned short* wot   = (unsigned short*)(ws + 14692352);     //  2 MB
  unsigned short* w1t   = (unsigned short*)(ws + 16789504);     //  4 MB
  unsigned short* w2t   = (unsigned short*)(ws + 20983808);     //  4 MB
  unsigned short* ctxb  = (unsigned short*)(ws + 25178112);     //  8 MB: attention output (bf16)
  float*          attn  = (float*)         (ws + 33566720);     // 16 MB: Wo output; later reused as FFN output f
  float*          fbuf  = attn;
  float*          qkv   = (float*)         (ws + 50343936);     // 48 MB: QKV activations (fp32)
  float*          out1  = qkv;                                  // 16 MB: reuse (qkv dead after attention)
  unsigned short* out1b = (unsigned short*)(ws + 50343936 + 16777216);  // 8 MB
  unsigned short* h1    = (unsigned short*)(ws + 50343936 + 25165824);  // 16 MB (bf16)
  // peak ws use: ~100.7 MB

  // --- prep ---
  k_cvt_bf16   <<<dim3(4096),  dim3(256), 0, stream>>>(x, xb);
  k_build_wqkvt<<<dim3(12288), dim3(256), 0, stream>>>(Wq, Wk, Wv, wqkvt);
  k_build_qbias<<<dim3(12),    dim3(256), 0, stream>>>(bq, bk, bv, qbias);
  k_transpose  <<<dim3(4096),  dim3(256), 0, stream>>>(Wo, wot, 10, MDIM);   // [1024][1024] -> [1024][1024]
  k_transpose  <<<dim3(8192),  dim3(256), 0, stream>>>(W1, w1t, 10, FFH);    // [1024][2048] -> [2048][1024]
  k_transpose  <<<dim3(8192),  dim3(256), 0, stream>>>(W2, w2t, 11, MDIM);   // [2048][1024] -> [1024][2048]

  // --- QKV projection: qkv[4096][3072] = xb @ wqkvt^T + qbias ---
  k_gemm<0,0><<<dim3(48, 64), dim3(256), 0, stream>>>(xb, wqkvt, qbias, qkv, 3072, 1024);
  // --- attention -> ctxb[4096][1024] bf16 ---
  k_attn<<<dim3(32, 32), dim3(256), 0, stream>>>(qkv, amask, ctxb);
  // --- output projection ---
  k_gemm<0,0><<<dim3(16, 64), dim3(256), 0, stream>>>(ctxb, wot, bo, attn, MDIM, 1024);
  // --- LN1(attn + x) -> out1 fp32, out1b bf16 ---
  k_ln<<<dim3(4096), dim3(256), 0, stream>>>(attn, x, g1, b1, out1, out1b);
  // --- FFN ---
  k_gemm<1,1><<<dim3(32, 64), dim3(256), 0, stream>>>(out1b, w1t, bias1, h1, FFH, 1024);
  k_gemm<0,0><<<dim3(16, 64), dim3(256), 0, stream>>>(h1, w2t, bias2, fbuf, MDIM, 2048);
  // --- LN2(out1 + f) -> d_out ---
  k_ln<<<dim3(4096), dim3(256), 0, stream>>>(fbuf, out1, g2, b2, (float*)d_out, nullptr);
}

// Round 3
// 484.410 us; speedup vs baseline: 3.9102x; 3.9102x over previous
//
#include <hip/hip_runtime.h>

#define MDIM 1024
#define FFH  2048
#define SEQ  2048
#define NEGV -1e9f

typedef __attribute__((ext_vector_type(8))) __bf16 bf16x8;
typedef __attribute__((ext_vector_type(4))) float floatx4;

__device__ __forceinline__ unsigned short f2bf(float f){
  union { float f; unsigned u; } v; v.f = f;
  unsigned u = v.u;
  u += 0x7fffu + ((u >> 16) & 1u);
  return (unsigned short)(u >> 16);
}

// ---------------- prep kernels ----------------
__global__ void k_cvt_bf16(const float* __restrict__ src, unsigned short* __restrict__ dst){
  int i = (blockIdx.x * 256 + threadIdx.x) * 4;
  float4 v = *(const float4*)(src + i);
  ushort4 o;
  o.x = f2bf(v.x); o.y = f2bf(v.y); o.z = f2bf(v.z); o.w = f2bf(v.w);
  *(ushort4*)(dst + i) = o;
}

// Wq/Wk/Wv [16][1024][64] -> fused B^T layout [3072][1024]; Wq rows pre-scaled by 1/8 (softmax scale, exact pow2).
__global__ void k_build_wqkvt(const float* __restrict__ Wq, const float* __restrict__ Wk,
                              const float* __restrict__ Wv, unsigned short* __restrict__ dst){
  int i = blockIdx.x * 256 + threadIdx.x;   // over 3072*1024
  int m  = i & 1023;
  int nr = i >> 10;                          // 0..3071
  const float* W = (nr < 1024) ? Wq : (nr < 2048) ? Wk : Wv;
  const float scl = (nr < 1024) ? 0.125f : 1.0f;
  int hd = nr & 1023;
  dst[i] = f2bf(W[((size_t)(hd >> 6) << 16) + ((size_t)m << 6) + (hd & 63)] * scl);
}

__global__ void k_build_qbias(const float* __restrict__ bq, const float* __restrict__ bk,
                              const float* __restrict__ bv, float* __restrict__ dst){
  int i = blockIdx.x * 256 + threadIdx.x;   // 3072
  dst[i] = (i < 1024) ? bq[i] * 0.125f : (i < 2048) ? bk[i - 1024] : bv[i - 2048];
}

// src [K][N] fp32 -> dst [N][K] bf16 (B^T layout), K = 1<<kshift
__global__ void k_transpose(const float* __restrict__ src, unsigned short* __restrict__ dst,
                            int kshift, int N){
  int i = blockIdx.x * 256 + threadIdx.x;   // over N*K
  int K = 1 << kshift;
  int k = i & (K - 1);
  int n = i >> kshift;
  dst[i] = f2bf(src[(size_t)k * N + n]);
}

// ---------------- bf16 MFMA GEMM: C[M][N] = A[M][K] @ Bt[N][K]^T + bias ----------------
template<int RELU, int OUTBF>
__global__ void __launch_bounds__(256) k_gemm(const unsigned short* __restrict__ A,
                                              const unsigned short* __restrict__ Bt,
                                              const float* __restrict__ bias,
                                              void* __restrict__ Cout, int N, int K){
  __shared__ unsigned short As[64 * 32];
  __shared__ unsigned short Bs[64 * 32];
  const int t = threadIdx.x;
  const int m0 = blockIdx.y << 6, n0 = blockIdx.x << 6;
  const int lane = t & 63, w = t >> 6;
  const int quad = lane >> 4, l16 = lane & 15;
  const int sr = t >> 2, sc = (t & 3) << 3;
  floatx4 acc[4];
  #pragma unroll
  for (int i = 0; i < 4; i++) acc[i] = (floatx4){0.f, 0.f, 0.f, 0.f};
  const unsigned short* Ag = A  + (size_t)(m0 + sr) * K + sc;
  const unsigned short* Bg = Bt + (size_t)(n0 + sr) * K + sc;
  for (int kb = 0; kb < K; kb += 32){
    uint4 av = *(const uint4*)(Ag + kb);
    uint4 bv = *(const uint4*)(Bg + kb);
    *(uint4*)&As[(sr << 5) + sc] = av;
    *(uint4*)&Bs[(sr << 5) + sc] = bv;
    __syncthreads();
    bf16x8 af = *(const bf16x8*)&As[(((w << 4) + l16) << 5) + (quad << 3)];
    #pragma unroll
    for (int ns = 0; ns < 4; ns++){
      bf16x8 bfr = *(const bf16x8*)&Bs[(((ns << 4) + l16) << 5) + (quad << 3)];
      acc[ns] = __builtin_amdgcn_mfma_f32_16x16x32_bf16(af, bfr, acc[ns], 0, 0, 0);
    }
    __syncthreads();
  }
  #pragma unroll
  for (int ns = 0; ns < 4; ns++){
    const int col = n0 + (ns << 4) + l16;
    const float bsv = bias[col];
    #pragma unroll
    for (int r = 0; r < 4; r++){
      const int row = m0 + (w << 4) + (quad << 2) + r;
      float v = acc[ns][r] + bsv;
      if (RELU) v = fmaxf(v, 0.f);
      if (OUTBF) ((unsigned short*)Cout)[(size_t)row * N + col] = f2bf(v);
      else       ((float*)Cout)[(size_t)row * N + col] = v;
    }
  }
}

// ---------------- MFMA flash attention, barrier-hardened ----------------
// Block = 4 waves, 64-q tile for one (b,h). Wave w owns q rows w*16..w*16+15.
// QK^T: A=Q frags (LDS-staged like k_gemm), B=K tile.  Scores round-trip LDS in fp32:
// written in C-layout (q=quad*4+r, key=ns*16+l16), re-read in q=l16 layout (lane owns
// q=l16, keys quad*16..+15).  Softmax state m/l/alpha in registers indexed q=l16 ==
// accO's column index, so rescale is a plain register multiply.  P (bf16) round-trips
// LDS for the PV B-fragment.  Every LDS producer->consumer edge is barrier-separated.
__global__ void __launch_bounds__(256) k_attn(const unsigned short* __restrict__ qkvb,
                                              const int* __restrict__ amask,
                                              unsigned short* __restrict__ ctxb){
  __shared__ __align__(16) unsigned short Qs[64 * 72];   // [q][d]
  __shared__ __align__(16) unsigned short Ks[64 * 72];   // [key][d]
  __shared__ __align__(16) unsigned short Vt[64 * 72];   // [d][key]
  __shared__ __align__(16) float Sls[4][16 * 68];        // per-wave scores [q][key] fp32
  __shared__ __align__(16) unsigned short Pl[4][16 * 72];// per-wave P [q][key] bf16
  __shared__ int msk[64];
  const int t = threadIdx.x;
  const int w = t >> 6, lane = t & 63;
  const int quad = lane >> 4, l16 = lane & 15;
  const int b = blockIdx.y >> 4, h = blockIdx.y & 15;
  const int q0 = blockIdx.x << 6;
  const int sr = t >> 2, sc = (t & 3) << 4;        // Q/K staging: row, 16-short chunk
  const int kg = t >> 4, dc = (t & 15) << 2;       // V staging: 4-key group, 4-d chunk

  // ---- stage Q tile, then load A-frags from LDS (k_gemm-verified pattern) ----
  {
    const unsigned short* qs = qkvb + (size_t)((b << 11) + q0 + sr) * 3072 + (h << 6) + sc;
    *(uint4*)&Qs[sr * 72 + sc]     = *(const uint4*)qs;
    *(uint4*)&Qs[sr * 72 + sc + 8] = *(const uint4*)(qs + 8);
  }
  __syncthreads();
  const bf16x8 qf0 = *(const bf16x8*)&Qs[((w << 4) + l16) * 72 + (quad << 3)];
  const bf16x8 qf1 = *(const bf16x8*)&Qs[((w << 4) + l16) * 72 + (quad << 3) + 32];

  floatx4 accO[4];
  #pragma unroll
  for (int i = 0; i < 4; i++) accO[i] = (floatx4){0.f, 0.f, 0.f, 0.f};
  float m_run = -3.0e38f, l_run = 0.f;             // for q = l16 (replicated over the 4 quads)

  const unsigned short* kbase = qkvb + (size_t)((b << 11) + sr) * 3072 + 1024 + (h << 6) + sc;
  const unsigned short* vbase = qkvb + (size_t)((b << 11) + (kg << 2)) * 3072 + 2048 + (h << 6) + dc;
  const int* mbase = amask + (b << 11);

  for (int k0 = 0; k0 < SEQ; k0 += 64){
    __syncthreads();                               // prev iteration's K/V readers done
    {
      const unsigned short* ks = kbase + (size_t)k0 * 3072;
      *(uint4*)&Ks[sr * 72 + sc]     = *(const uint4*)ks;
      *(uint4*)&Ks[sr * 72 + sc + 8] = *(const uint4*)(ks + 8);
    }
    {
      const unsigned short* vs = vbase + (size_t)k0 * 3072;
      ushort4 r0 = *(const ushort4*)(vs);
      ushort4 r1 = *(const ushort4*)(vs + 3072);
      ushort4 r2 = *(const ushort4*)(vs + 2 * 3072);
      ushort4 r3 = *(const ushort4*)(vs + 3 * 3072);
      ushort4 c;
      c.x = r0.x; c.y = r1.x; c.z = r2.x; c.w = r3.x; *(ushort4*)&Vt[(dc + 0) * 72 + (kg << 2)] = c;
      c.x = r0.y; c.y = r1.y; c.z = r2.y; c.w = r3.y; *(ushort4*)&Vt[(dc + 1) * 72 + (kg << 2)] = c;
      c.x = r0.z; c.y = r1.z; c.z = r2.z; c.w = r3.z; *(ushort4*)&Vt[(dc + 2) * 72 + (kg << 2)] = c;
      c.x = r0.w; c.y = r1.w; c.z = r2.w; c.w = r3.w; *(ushort4*)&Vt[(dc + 3) * 72 + (kg << 2)] = c;
    }
    if (t < 64) msk[t] = mbase[k0 + t];
    __syncthreads();

    // ---- QK^T: S[16q][64key] per wave ----
    floatx4 sc4[4];
    #pragma unroll
    for (int ns = 0; ns < 4; ns++){
      sc4[ns] = (floatx4){0.f, 0.f, 0.f, 0.f};
      const unsigned short* kp = &Ks[((ns << 4) + l16) * 72 + (quad << 3)];
      bf16x8 kf0 = *(const bf16x8*)(kp);
      bf16x8 kf1 = *(const bf16x8*)(kp + 32);
      sc4[ns] = __builtin_amdgcn_mfma_f32_16x16x32_bf16(qf0, kf0, sc4[ns], 0, 0, 0);
      sc4[ns] = __builtin_amdgcn_mfma_f32_16x16x32_bf16(qf1, kf1, sc4[ns], 0, 0, 0);
    }
    // ---- S -> LDS (C-layout write: q = quad*4+r, key = ns*16+l16) ----
    #pragma unroll
    for (int ns = 0; ns < 4; ns++)
      #pragma unroll
      for (int r = 0; r < 4; r++)
        Sls[w][((quad << 2) + r) * 68 + (ns << 4) + l16] = sc4[ns][r];
    __syncthreads();

    // ---- re-read in q=l16 layout: lane owns q=l16, keys quad*16..quad*16+15 ----
    float sv[16];
    {
      const float4* srow = (const float4*)&Sls[w][l16 * 68 + (quad << 4)];
      #pragma unroll
      for (int e4 = 0; e4 < 4; e4++){
        float4 v = srow[e4];
        sv[e4 * 4 + 0] = v.x; sv[e4 * 4 + 1] = v.y; sv[e4 * 4 + 2] = v.z; sv[e4 * 4 + 3] = v.w;
      }
    }
    #pragma unroll
    for (int e = 0; e < 16; e++)
      if (msk[(quad << 4) + e] == 0) sv[e] = NEGV;
    float tmax = sv[0];
    #pragma unroll
    for (int e = 1; e < 16; e++) tmax = fmaxf(tmax, sv[e]);
    tmax = fmaxf(tmax, __shfl_xor(tmax, 16));
    tmax = fmaxf(tmax, __shfl_xor(tmax, 32));
    const float mnew = fmaxf(m_run, tmax);
    const float alpha = __expf(m_run - mnew);
    float pv[16], lsum = 0.f;
    #pragma unroll
    for (int e = 0; e < 16; e++){ pv[e] = __expf(sv[e] - mnew); lsum += pv[e]; }
    lsum += __shfl_xor(lsum, 16);
    lsum += __shfl_xor(lsum, 32);
    l_run = l_run * alpha + lsum;
    m_run = mnew;
    // ---- P -> LDS (row-major [q=l16][key=quad*16+e], bf16) ----
    #pragma unroll
    for (int e = 0; e < 16; e++)
      Pl[w][l16 * 72 + (quad << 4) + e] = f2bf(pv[e]);
    __syncthreads();

    // ---- O^T[d][q] += V^T[d][k] P^T[k][q]; rescale accO by alpha (both indexed q=l16) ----
    const bf16x8 pf0 = *(const bf16x8*)&Pl[w][l16 * 72 + (quad << 3)];
    const bf16x8 pf1 = *(const bf16x8*)&Pl[w][l16 * 72 + (quad << 3) + 32];
    #pragma unroll
    for (int mt = 0; mt < 4; mt++){
      #pragma unroll
      for (int i = 0; i < 4; i++) accO[mt][i] *= alpha;
      const unsigned short* vp = &Vt[((mt << 4) + l16) * 72 + (quad << 3)];
      bf16x8 vf0 = *(const bf16x8*)(vp);
      bf16x8 vf1 = *(const bf16x8*)(vp + 32);
      accO[mt] = __builtin_amdgcn_mfma_f32_16x16x32_bf16(vf0, pf0, accO[mt], 0, 0, 0);
      accO[mt] = __builtin_amdgcn_mfma_f32_16x16x32_bf16(vf1, pf1, accO[mt], 0, 0, 0);
    }
  }
  // ---- epilogue: O[q][d] = accO / l_run; q = l16 (col), d = mt*16 + quad*4 + reg (row) ----
  const float linv = 1.f / l_run;
  unsigned short* orow = ctxb + (size_t)((b << 11) + q0 + (w << 4) + l16) * 1024 + (h << 6);
  #pragma unroll
  for (int mt = 0; mt < 4; mt++){
    ushort4 o;
    o.x = f2bf(accO[mt][0] * linv);
    o.y = f2bf(accO[mt][1] * linv);
    o.z = f2bf(accO[mt][2] * linv);
    o.w = f2bf(accO[mt][3] * linv);
    *(ushort4*)&orow[(mt << 4) + (quad << 2)] = o;
  }
}

// ---------------- residual + LayerNorm (1024 cols, one block per row) ----------------
__global__ void __launch_bounds__(256) k_ln(const float* __restrict__ a, const float* __restrict__ res,
                                            const float* __restrict__ gg, const float* __restrict__ bb,
                                            float* __restrict__ out, unsigned short* __restrict__ outb){
  const int row = blockIdx.x, t = threadIdx.x;
  const float4 av = ((const float4*)(a   + (size_t)row * 1024))[t];
  const float4 rv = ((const float4*)(res + (size_t)row * 1024))[t];
  float4 v; v.x = av.x + rv.x; v.y = av.y + rv.y; v.z = av.z + rv.z; v.w = av.w + rv.w;
  float sum = v.x + v.y + v.z + v.w;
  float ss  = v.x * v.x + v.y * v.y + v.z * v.z + v.w * v.w;
  #pragma unroll
  for (int off = 32; off > 0; off >>= 1){
    sum += __shfl_down(sum, off);
    ss  += __shfl_down(ss, off);
  }
  __shared__ float red[8];
  const int w = t >> 6;
  if ((t & 63) == 0){ red[w] = sum; red[4 + w] = ss; }
  __syncthreads();
  const float S  = red[0] + red[1] + red[2] + red[3];
  const float SS = red[4] + red[5] + red[6] + red[7];
  const float mu  = S * (1.f / 1024.f);
  const float var = SS * (1.f / 1024.f) - mu * mu;
  const float rs  = rsqrtf(var + 1e-5f);
  const float4 gv = ((const float4*)gg)[t];
  const float4 bv = ((const float4*)bb)[t];
  float4 o;
  o.x = (v.x - mu) * rs * gv.x + bv.x;
  o.y = (v.y - mu) * rs * gv.y + bv.y;
  o.z = (v.z - mu) * rs * gv.z + bv.z;
  o.w = (v.w - mu) * rs * gv.w + bv.w;
  ((float4*)(out + (size_t)row * 1024))[t] = o;
  if (outb){
    ushort4 ob; ob.x = f2bf(o.x); ob.y = f2bf(o.y); ob.z = f2bf(o.z); ob.w = f2bf(o.w);
    ((ushort4*)(outb + (size_t)row * 1024))[t] = ob;
  }
}

extern "C" void kernel_launch(void* const* d_in, const int* in_sizes, int n_in,
                              void* d_out, int out_size, void* d_ws, size_t ws_size,
                              hipStream_t stream){
  const float* x     = (const float*)d_in[0];
  const int*   amask = (const int*)d_in[1];
  const float* Wq    = (const float*)d_in[2];
  const float* bq    = (const float*)d_in[3];
  const float* Wk    = (const float*)d_in[4];
  const float* bk    = (const float*)d_in[5];
  const float* Wv    = (const float*)d_in[6];
  const float* bv    = (const float*)d_in[7];
  const float* Wo    = (const float*)d_in[8];
  const float* bo    = (const float*)d_in[9];
  const float* g1    = (const float*)d_in[10];
  const float* b1    = (const float*)d_in[11];
  const float* W1    = (const float*)d_in[12];
  const float* bias1 = (const float*)d_in[13];
  const float* W2    = (const float*)d_in[14];
  const float* bias2 = (const float*)d_in[15];
  const float* g2    = (const float*)d_in[16];
  const float* b2    = (const float*)d_in[17];

  char* ws = (char*)d_ws;
  unsigned short* xb    = (unsigned short*)(ws + 0);            //  8 MB
  unsigned short* wqkvt = (unsigned short*)(ws + 8388608);      //  6 MB
  float*          qbias = (float*)         (ws + 14680064);     // 12 KB
  unsigned short* wot   = (unsigned short*)(ws + 14692352);     //  2 MB
  unsigned short* w1t   = (unsigned short*)(ws + 16789504);     //  4 MB
  unsigned short* w2t   = (unsigned short*)(ws + 20983808);     //  4 MB
  unsigned short* ctxb  = (unsigned short*)(ws + 25178112);     //  8 MB
  float*          attn  = (float*)         (ws + 33566720);     // 16 MB (also FFN out)
  float*          fbuf  = attn;
  unsigned short* qkvb  = (unsigned short*)(ws + 50343936);     // 24 MB: QKV bf16 [4096][3072]
  float*          out1  = (float*)         (ws + 50343936);     // reuse (qkvb dead after attn)
  unsigned short* out1b = (unsigned short*)(ws + 50343936 + 25165824);  // 8 MB
  unsigned short* h1    = (unsigned short*)(ws + 50343936 + 33554432);  // 16 MB

  // --- prep ---
  k_cvt_bf16   <<<dim3(4096),  dim3(256), 0, stream>>>(x, xb);
  k_build_wqkvt<<<dim3(12288), dim3(256), 0, stream>>>(Wq, Wk, Wv, wqkvt);
  k_build_qbias<<<dim3(12),    dim3(256), 0, stream>>>(bq, bk, bv, qbias);
  k_transpose  <<<dim3(4096),  dim3(256), 0, stream>>>(Wo, wot, 10, MDIM);
  k_transpose  <<<dim3(8192),  dim3(256), 0, stream>>>(W1, w1t, 10, FFH);
  k_transpose  <<<dim3(8192),  dim3(256), 0, stream>>>(W2, w2t, 11, MDIM);

  // --- QKV projection -> bf16 (Q pre-scaled by 1/8 via Wq/bq) ---
  k_gemm<0,1><<<dim3(48, 64), dim3(256), 0, stream>>>(xb, wqkvt, qbias, qkvb, 3072, 1024);
  // --- MFMA flash attention -> ctxb bf16 ---
  k_attn<<<dim3(32, 32), dim3(256), 0, stream>>>(qkvb, amask, ctxb);
  // --- output projection ---
  k_gemm<0,0><<<dim3(16, 64), dim3(256), 0, stream>>>(ctxb, wot, bo, attn, MDIM, 1024);
  // --- LN1(attn + x) ---
  k_ln<<<dim3(4096), dim3(256), 0, stream>>>(attn, x, g1, b1, out1, out1b);
  // --- FFN ---
  k_gemm<1,1><<<dim3(32, 64), dim3(256), 0, stream>>>(out1b, w1t, bias1, h1, FFH, 1024);
  k_gemm<0,0><<<dim3(16, 64), dim3(256), 0, stream>>>(h1, w2t, bias2, fbuf, MDIM, 2048);
  // --- LN2(out1 + f) -> d_out ---
  k_ln<<<dim3(4096), dim3(256), 0, stream>>>(fbuf, out1, g2, b2, (float*)d_out, nullptr);
}

// Round 4
// 463.493 us; speedup vs baseline: 4.0867x; 1.0451x over previous
//
#include <hip/hip_runtime.h>

#define MDIM 1024
#define FFH  2048
#define SEQ  2048
#define NEGV -1e9f

typedef __attribute__((ext_vector_type(8))) __bf16 bf16x8;
typedef __attribute__((ext_vector_type(4))) float floatx4;
typedef __attribute__((address_space(3))) unsigned int lds_uint;
typedef const __attribute__((address_space(1))) unsigned int g_uint;

__device__ __forceinline__ unsigned short f2bf(float f){
  union { float f; unsigned u; } v; v.f = f;
  unsigned u = v.u;
  u += 0x7fffu + ((u >> 16) & 1u);
  return (unsigned short)(u >> 16);
}

// ---------------- prep kernels ----------------
__global__ void k_cvt_bf16(const float* __restrict__ src, unsigned short* __restrict__ dst){
  int i = (blockIdx.x * 256 + threadIdx.x) * 4;
  float4 v = *(const float4*)(src + i);
  ushort4 o;
  o.x = f2bf(v.x); o.y = f2bf(v.y); o.z = f2bf(v.z); o.w = f2bf(v.w);
  *(ushort4*)(dst + i) = o;
}

// Wq/Wk/Wv [16][1024][64] -> fused B^T layout [3072][1024]; Wq rows pre-scaled by 1/8 (softmax scale, exact pow2).
__global__ void k_build_wqkvt(const float* __restrict__ Wq, const float* __restrict__ Wk,
                              const float* __restrict__ Wv, unsigned short* __restrict__ dst){
  int i = blockIdx.x * 256 + threadIdx.x;   // over 3072*1024
  int m  = i & 1023;
  int nr = i >> 10;                          // 0..3071
  const float* W = (nr < 1024) ? Wq : (nr < 2048) ? Wk : Wv;
  const float scl = (nr < 1024) ? 0.125f : 1.0f;
  int hd = nr & 1023;
  dst[i] = f2bf(W[((size_t)(hd >> 6) << 16) + ((size_t)m << 6) + (hd & 63)] * scl);
}

__global__ void k_build_qbias(const float* __restrict__ bq, const float* __restrict__ bk,
                              const float* __restrict__ bv, float* __restrict__ dst){
  int i = blockIdx.x * 256 + threadIdx.x;   // 3072
  dst[i] = (i < 1024) ? bq[i] * 0.125f : (i < 2048) ? bk[i - 1024] : bv[i - 2048];
}

// src [K][N] fp32 -> dst [N][K] bf16 (B^T layout), K = 1<<kshift
__global__ void k_transpose(const float* __restrict__ src, unsigned short* __restrict__ dst,
                            int kshift, int N){
  int i = blockIdx.x * 256 + threadIdx.x;   // over N*K
  int K = 1 << kshift;
  int k = i & (K - 1);
  int n = i >> kshift;
  dst[i] = f2bf(src[(size_t)k * N + n]);
}

// ---------------- bf16 MFMA GEMM, 128x128 tile + global_load_lds (m97 structure) ----------------
// C[M][N] = A[M][K] @ Bt[N][K]^T + bias.  256 threads = 4 waves; wave w owns the 64x64
// quadrant (rows (w&1)*64, cols (w>>1)*64), 4x4 grid of 16x16x32 MFMAs.
// LDS tiles are UNPADDED [128][32] bf16: global_load_lds requires dest = wave-uniform
// base + lane*16B, and thread t's (row=t>>2, col=(t&3)*8) maps to byte offset t*16.
template<int RELU, int OUTBF>
__global__ void __launch_bounds__(256) k_gemm128(const unsigned short* __restrict__ A,
                                                 const unsigned short* __restrict__ Bt,
                                                 const float* __restrict__ bias,
                                                 void* __restrict__ Cout, int N, int K){
  __shared__ unsigned short As[128 * 32];
  __shared__ unsigned short Bs[128 * 32];
  const int t = threadIdx.x;
  const int m0 = blockIdx.y << 7, n0 = blockIdx.x << 7;
  const int lane = t & 63, w = t >> 6;
  const int quad = lane >> 4, l16 = lane & 15;
  const int mw = (w & 1) << 6, nw = (w >> 1) << 6;
  floatx4 acc[4][4];
  #pragma unroll
  for (int i = 0; i < 4; i++)
    #pragma unroll
    for (int j = 0; j < 4; j++) acc[i][j] = (floatx4){0.f, 0.f, 0.f, 0.f};
  const unsigned short* Ag  = A  + (size_t)(m0 + (t >> 2)) * K + ((t & 3) << 3);
  const unsigned short* Ag2 = Ag + (size_t)64 * K;
  const unsigned short* Bg  = Bt + (size_t)(n0 + (t >> 2)) * K + ((t & 3) << 3);
  const unsigned short* Bg2 = Bg + (size_t)64 * K;
  for (int kb = 0; kb < K; kb += 32){
    __builtin_amdgcn_global_load_lds((g_uint*)(Ag  + kb), (lds_uint*)&As[t << 3],          16, 0, 0);
    __builtin_amdgcn_global_load_lds((g_uint*)(Ag2 + kb), (lds_uint*)&As[2048 + (t << 3)], 16, 0, 0);
    __builtin_amdgcn_global_load_lds((g_uint*)(Bg  + kb), (lds_uint*)&Bs[t << 3],          16, 0, 0);
    __builtin_amdgcn_global_load_lds((g_uint*)(Bg2 + kb), (lds_uint*)&Bs[2048 + (t << 3)], 16, 0, 0);
    __syncthreads();   // compiler drains vmcnt(0) before s_barrier -> LDS data ready
    bf16x8 af[4], bf[4];
    #pragma unroll
    for (int mt = 0; mt < 4; mt++)
      af[mt] = *(const bf16x8*)&As[((mw + (mt << 4) + l16) << 5) + (quad << 3)];
    #pragma unroll
    for (int nt = 0; nt < 4; nt++)
      bf[nt] = *(const bf16x8*)&Bs[((nw + (nt << 4) + l16) << 5) + (quad << 3)];
    #pragma unroll
    for (int mt = 0; mt < 4; mt++)
      #pragma unroll
      for (int nt = 0; nt < 4; nt++)
        acc[mt][nt] = __builtin_amdgcn_mfma_f32_16x16x32_bf16(af[mt], bf[nt], acc[mt][nt], 0, 0, 0);
    __syncthreads();   // all reads done before next iteration's staging
  }
  // C/D layout: col = lane&15, row = quad*4 + reg   [measured m89/m91]
  #pragma unroll
  for (int nt = 0; nt < 4; nt++){
    const int col = n0 + nw + (nt << 4) + l16;
    const float bsv = bias[col];
    #pragma unroll
    for (int mt = 0; mt < 4; mt++){
      const int row = m0 + mw + (mt << 4) + (quad << 2);
      #pragma unroll
      for (int r = 0; r < 4; r++){
        float v = acc[mt][nt][r] + bsv;
        if (RELU) v = fmaxf(v, 0.f);
        if (OUTBF) ((unsigned short*)Cout)[(size_t)(row + r) * N + col] = f2bf(v);
        else       ((float*)Cout)[(size_t)(row + r) * N + col] = v;
      }
    }
  }
}

// ---------------- MFMA flash attention, barrier-hardened (round-3 verified) ----------------
__global__ void __launch_bounds__(256) k_attn(const unsigned short* __restrict__ qkvb,
                                              const int* __restrict__ amask,
                                              unsigned short* __restrict__ ctxb){
  __shared__ __align__(16) unsigned short Qs[64 * 72];   // [q][d]
  __shared__ __align__(16) unsigned short Ks[64 * 72];   // [key][d]
  __shared__ __align__(16) unsigned short Vt[64 * 72];   // [d][key]
  __shared__ __align__(16) float Sls[4][16 * 68];        // per-wave scores [q][key] fp32
  __shared__ __align__(16) unsigned short Pl[4][16 * 72];// per-wave P [q][key] bf16
  __shared__ int msk[64];
  const int t = threadIdx.x;
  const int w = t >> 6, lane = t & 63;
  const int quad = lane >> 4, l16 = lane & 15;
  const int b = blockIdx.y >> 4, h = blockIdx.y & 15;
  const int q0 = blockIdx.x << 6;
  const int sr = t >> 2, sc = (t & 3) << 4;        // Q/K staging: row, 16-short chunk
  const int kg = t >> 4, dc = (t & 15) << 2;       // V staging: 4-key group, 4-d chunk

  {
    const unsigned short* qs = qkvb + (size_t)((b << 11) + q0 + sr) * 3072 + (h << 6) + sc;
    *(uint4*)&Qs[sr * 72 + sc]     = *(const uint4*)qs;
    *(uint4*)&Qs[sr * 72 + sc + 8] = *(const uint4*)(qs + 8);
  }
  __syncthreads();
  const bf16x8 qf0 = *(const bf16x8*)&Qs[((w << 4) + l16) * 72 + (quad << 3)];
  const bf16x8 qf1 = *(const bf16x8*)&Qs[((w << 4) + l16) * 72 + (quad << 3) + 32];

  floatx4 accO[4];
  #pragma unroll
  for (int i = 0; i < 4; i++) accO[i] = (floatx4){0.f, 0.f, 0.f, 0.f};
  float m_run = -3.0e38f, l_run = 0.f;             // for q = l16 (replicated over the 4 quads)

  const unsigned short* kbase = qkvb + (size_t)((b << 11) + sr) * 3072 + 1024 + (h << 6) + sc;
  const unsigned short* vbase = qkvb + (size_t)((b << 11) + (kg << 2)) * 3072 + 2048 + (h << 6) + dc;
  const int* mbase = amask + (b << 11);

  for (int k0 = 0; k0 < SEQ; k0 += 64){
    __syncthreads();
    {
      const unsigned short* ks = kbase + (size_t)k0 * 3072;
      *(uint4*)&Ks[sr * 72 + sc]     = *(const uint4*)ks;
      *(uint4*)&Ks[sr * 72 + sc + 8] = *(const uint4*)(ks + 8);
    }
    {
      const unsigned short* vs = vbase + (size_t)k0 * 3072;
      ushort4 r0 = *(const ushort4*)(vs);
      ushort4 r1 = *(const ushort4*)(vs + 3072);
      ushort4 r2 = *(const ushort4*)(vs + 2 * 3072);
      ushort4 r3 = *(const ushort4*)(vs + 3 * 3072);
      ushort4 c;
      c.x = r0.x; c.y = r1.x; c.z = r2.x; c.w = r3.x; *(ushort4*)&Vt[(dc + 0) * 72 + (kg << 2)] = c;
      c.x = r0.y; c.y = r1.y; c.z = r2.y; c.w = r3.y; *(ushort4*)&Vt[(dc + 1) * 72 + (kg << 2)] = c;
      c.x = r0.z; c.y = r1.z; c.z = r2.z; c.w = r3.z; *(ushort4*)&Vt[(dc + 2) * 72 + (kg << 2)] = c;
      c.x = r0.w; c.y = r1.w; c.z = r2.w; c.w = r3.w; *(ushort4*)&Vt[(dc + 3) * 72 + (kg << 2)] = c;
    }
    if (t < 64) msk[t] = mbase[k0 + t];
    __syncthreads();

    floatx4 sc4[4];
    #pragma unroll
    for (int ns = 0; ns < 4; ns++){
      sc4[ns] = (floatx4){0.f, 0.f, 0.f, 0.f};
      const unsigned short* kp = &Ks[((ns << 4) + l16) * 72 + (quad << 3)];
      bf16x8 kf0 = *(const bf16x8*)(kp);
      bf16x8 kf1 = *(const bf16x8*)(kp + 32);
      sc4[ns] = __builtin_amdgcn_mfma_f32_16x16x32_bf16(qf0, kf0, sc4[ns], 0, 0, 0);
      sc4[ns] = __builtin_amdgcn_mfma_f32_16x16x32_bf16(qf1, kf1, sc4[ns], 0, 0, 0);
    }
    #pragma unroll
    for (int ns = 0; ns < 4; ns++)
      #pragma unroll
      for (int r = 0; r < 4; r++)
        Sls[w][((quad << 2) + r) * 68 + (ns << 4) + l16] = sc4[ns][r];
    __syncthreads();

    float sv[16];
    {
      const float4* srow = (const float4*)&Sls[w][l16 * 68 + (quad << 4)];
      #pragma unroll
      for (int e4 = 0; e4 < 4; e4++){
        float4 v = srow[e4];
        sv[e4 * 4 + 0] = v.x; sv[e4 * 4 + 1] = v.y; sv[e4 * 4 + 2] = v.z; sv[e4 * 4 + 3] = v.w;
      }
    }
    #pragma unroll
    for (int e = 0; e < 16; e++)
      if (msk[(quad << 4) + e] == 0) sv[e] = NEGV;
    float tmax = sv[0];
    #pragma unroll
    for (int e = 1; e < 16; e++) tmax = fmaxf(tmax, sv[e]);
    tmax = fmaxf(tmax, __shfl_xor(tmax, 16));
    tmax = fmaxf(tmax, __shfl_xor(tmax, 32));
    const float mnew = fmaxf(m_run, tmax);
    const float alpha = __expf(m_run - mnew);
    float pv[16], lsum = 0.f;
    #pragma unroll
    for (int e = 0; e < 16; e++){ pv[e] = __expf(sv[e] - mnew); lsum += pv[e]; }
    lsum += __shfl_xor(lsum, 16);
    lsum += __shfl_xor(lsum, 32);
    l_run = l_run * alpha + lsum;
    m_run = mnew;
    #pragma unroll
    for (int e = 0; e < 16; e++)
      Pl[w][l16 * 72 + (quad << 4) + e] = f2bf(pv[e]);
    __syncthreads();

    const bf16x8 pf0 = *(const bf16x8*)&Pl[w][l16 * 72 + (quad << 3)];
    const bf16x8 pf1 = *(const bf16x8*)&Pl[w][l16 * 72 + (quad << 3) + 32];
    #pragma unroll
    for (int mt = 0; mt < 4; mt++){
      #pragma unroll
      for (int i = 0; i < 4; i++) accO[mt][i] *= alpha;
      const unsigned short* vp = &Vt[((mt << 4) + l16) * 72 + (quad << 3)];
      bf16x8 vf0 = *(const bf16x8*)(vp);
      bf16x8 vf1 = *(const bf16x8*)(vp + 32);
      accO[mt] = __builtin_amdgcn_mfma_f32_16x16x32_bf16(vf0, pf0, accO[mt], 0, 0, 0);
      accO[mt] = __builtin_amdgcn_mfma_f32_16x16x32_bf16(vf1, pf1, accO[mt], 0, 0, 0);
    }
  }
  const float linv = 1.f / l_run;
  unsigned short* orow = ctxb + (size_t)((b << 11) + q0 + (w << 4) + l16) * 1024 + (h << 6);
  #pragma unroll
  for (int mt = 0; mt < 4; mt++){
    ushort4 o;
    o.x = f2bf(accO[mt][0] * linv);
    o.y = f2bf(accO[mt][1] * linv);
    o.z = f2bf(accO[mt][2] * linv);
    o.w = f2bf(accO[mt][3] * linv);
    *(ushort4*)&orow[(mt << 4) + (quad << 2)] = o;
  }
}

// ---------------- residual + LayerNorm (1024 cols, one block per row) ----------------
__global__ void __launch_bounds__(256) k_ln(const float* __restrict__ a, const float* __restrict__ res,
                                            const float* __restrict__ gg, const float* __restrict__ bb,
                                            float* __restrict__ out, unsigned short* __restrict__ outb){
  const int row = blockIdx.x, t = threadIdx.x;
  const float4 av = ((const float4*)(a   + (size_t)row * 1024))[t];
  const float4 rv = ((const float4*)(res + (size_t)row * 1024))[t];
  float4 v; v.x = av.x + rv.x; v.y = av.y + rv.y; v.z = av.z + rv.z; v.w = av.w + rv.w;
  float sum = v.x + v.y + v.z + v.w;
  float ss  = v.x * v.x + v.y * v.y + v.z * v.z + v.w * v.w;
  #pragma unroll
  for (int off = 32; off > 0; off >>= 1){
    sum += __shfl_down(sum, off);
    ss  += __shfl_down(ss, off);
  }
  __shared__ float red[8];
  const int w = t >> 6;
  if ((t & 63) == 0){ red[w] = sum; red[4 + w] = ss; }
  __syncthreads();
  const float S  = red[0] + red[1] + red[2] + red[3];
  const float SS = red[4] + red[5] + red[6] + red[7];
  const float mu  = S * (1.f / 1024.f);
  const float var = SS * (1.f / 1024.f) - mu * mu;
  const float rs  = rsqrtf(var + 1e-5f);
  const float4 gv = ((const float4*)gg)[t];
  const float4 bv = ((const float4*)bb)[t];
  float4 o;
  o.x = (v.x - mu) * rs * gv.x + bv.x;
  o.y = (v.y - mu) * rs * gv.y + bv.y;
  o.z = (v.z - mu) * rs * gv.z + bv.z;
  o.w = (v.w - mu) * rs * gv.w + bv.w;
  ((float4*)(out + (size_t)row * 1024))[t] = o;
  if (outb){
    ushort4 ob; ob.x = f2bf(o.x); ob.y = f2bf(o.y); ob.z = f2bf(o.z); ob.w = f2bf(o.w);
    ((ushort4*)(outb + (size_t)row * 1024))[t] = ob;
  }
}

extern "C" void kernel_launch(void* const* d_in, const int* in_sizes, int n_in,
                              void* d_out, int out_size, void* d_ws, size_t ws_size,
                              hipStream_t stream){
  const float* x     = (const float*)d_in[0];
  const int*   amask = (const int*)d_in[1];
  const float* Wq    = (const float*)d_in[2];
  const float* bq    = (const float*)d_in[3];
  const float* Wk    = (const float*)d_in[4];
  const float* bk    = (const float*)d_in[5];
  const float* Wv    = (const float*)d_in[6];
  const float* bv    = (const float*)d_in[7];
  const float* Wo    = (const float*)d_in[8];
  const float* bo    = (const float*)d_in[9];
  const float* g1    = (const float*)d_in[10];
  const float* b1    = (const float*)d_in[11];
  const float* W1    = (const float*)d_in[12];
  const float* bias1 = (const float*)d_in[13];
  const float* W2    = (const float*)d_in[14];
  const float* bias2 = (const float*)d_in[15];
  const float* g2    = (const float*)d_in[16];
  const float* b2    = (const float*)d_in[17];

  char* ws = (char*)d_ws;
  unsigned short* xb    = (unsigned short*)(ws + 0);            //  8 MB
  unsigned short* wqkvt = (unsigned short*)(ws + 8388608);      //  6 MB
  float*          qbias = (float*)         (ws + 14680064);     // 12 KB
  unsigned short* wot   = (unsigned short*)(ws + 14692352);     //  2 MB
  unsigned short* w1t   = (unsigned short*)(ws + 16789504);     //  4 MB
  unsigned short* w2t   = (unsigned short*)(ws + 20983808);     //  4 MB
  unsigned short* ctxb  = (unsigned short*)(ws + 25178112);     //  8 MB
  float*          attn  = (float*)         (ws + 33566720);     // 16 MB (also FFN out)
  float*          fbuf  = attn;
  unsigned short* qkvb  = (unsigned short*)(ws + 50343936);     // 24 MB: QKV bf16 [4096][3072]
  float*          out1  = (float*)         (ws + 50343936);     // reuse (qkvb dead after attn)
  unsigned short* out1b = (unsigned short*)(ws + 50343936 + 25165824);  // 8 MB
  unsigned short* h1    = (unsigned short*)(ws + 50343936 + 33554432);  // 16 MB

  // --- prep ---
  k_cvt_bf16   <<<dim3(4096),  dim3(256), 0, stream>>>(x, xb);
  k_build_wqkvt<<<dim3(12288), dim3(256), 0, stream>>>(Wq, Wk, Wv, wqkvt);
  k_build_qbias<<<dim3(12),    dim3(256), 0, stream>>>(bq, bk, bv, qbias);
  k_transpose  <<<dim3(4096),  dim3(256), 0, stream>>>(Wo, wot, 10, MDIM);
  k_transpose  <<<dim3(8192),  dim3(256), 0, stream>>>(W1, w1t, 10, FFH);
  k_transpose  <<<dim3(8192),  dim3(256), 0, stream>>>(W2, w2t, 11, MDIM);

  // --- QKV projection -> bf16 (Q pre-scaled by 1/8 via Wq/bq) ---
  k_gemm128<0,1><<<dim3(24, 32), dim3(256), 0, stream>>>(xb, wqkvt, qbias, qkvb, 3072, 1024);
  // --- MFMA flash attention -> ctxb bf16 ---
  k_attn<<<dim3(32, 32), dim3(256), 0, stream>>>(qkvb, amask, ctxb);
  // --- output projection ---
  k_gemm128<0,0><<<dim3(8, 32), dim3(256), 0, stream>>>(ctxb, wot, bo, attn, MDIM, 1024);
  // --- LN1(attn + x) ---
  k_ln<<<dim3(4096), dim3(256), 0, stream>>>(attn, x, g1, b1, out1, out1b);
  // --- FFN ---
  k_gemm128<1,1><<<dim3(16, 32), dim3(256), 0, stream>>>(out1b, w1t, bias1, h1, FFH, 1024);
  k_gemm128<0,0><<<dim3(8, 32), dim3(256), 0, stream>>>(h1, w2t, bias2, fbuf, MDIM, 2048);
  // --- LN2(out1 + f) -> d_out ---
  k_ln<<<dim3(4096), dim3(256), 0, stream>>>(fbuf, out1, g2, b2, (float*)d_out, nullptr);
}

// Round 5
// 436.409 us; speedup vs baseline: 4.3403x; 1.0621x over previous
//
#include <hip/hip_runtime.h>

#define MDIM 1024
#define FFH  2048
#define SEQ  2048
#define NEGV -1e9f

typedef __attribute__((ext_vector_type(8))) __bf16 bf16x8;
typedef __attribute__((ext_vector_type(4))) float floatx4;
typedef __attribute__((address_space(3))) unsigned int lds_uint;
typedef const __attribute__((address_space(1))) unsigned int g_uint;

__device__ __forceinline__ unsigned short f2bf(float f){
  union { float f; unsigned u; } v; v.f = f;
  unsigned u = v.u;
  u += 0x7fffu + ((u >> 16) & 1u);
  return (unsigned short)(u >> 16);
}
__device__ __forceinline__ unsigned short f2bf_tr(float f){   // truncating (softmax-internal only)
  union { float f; unsigned u; } v; v.f = f;
  return (unsigned short)(v.u >> 16);
}
__device__ __forceinline__ float bf2f(unsigned short s){
  union { unsigned u; float f; } v; v.u = ((unsigned)s) << 16;
  return v.f;
}

// ---------------- prep kernels ----------------
__global__ void k_cvt_bf16(const float* __restrict__ src, unsigned short* __restrict__ dst){
  int i = (blockIdx.x * 256 + threadIdx.x) * 4;
  float4 v = *(const float4*)(src + i);
  ushort4 o;
  o.x = f2bf(v.x); o.y = f2bf(v.y); o.z = f2bf(v.z); o.w = f2bf(v.w);
  *(ushort4*)(dst + i) = o;
}

// Wq/Wk/Wv [16][1024][64] -> fused B^T layout [3072][1024]; Wq rows pre-scaled by 1/8 (softmax scale, exact pow2).
__global__ void k_build_wqkvt(const float* __restrict__ Wq, const float* __restrict__ Wk,
                              const float* __restrict__ Wv, unsigned short* __restrict__ dst){
  int i = blockIdx.x * 256 + threadIdx.x;   // over 3072*1024
  int m  = i & 1023;
  int nr = i >> 10;                          // 0..3071
  const float* W = (nr < 1024) ? Wq : (nr < 2048) ? Wk : Wv;
  const float scl = (nr < 1024) ? 0.125f : 1.0f;
  int hd = nr & 1023;
  dst[i] = f2bf(W[((size_t)(hd >> 6) << 16) + ((size_t)m << 6) + (hd & 63)] * scl);
}

__global__ void k_build_qbias(const float* __restrict__ bq, const float* __restrict__ bk,
                              const float* __restrict__ bv, float* __restrict__ dst){
  int i = blockIdx.x * 256 + threadIdx.x;   // 3072
  dst[i] = (i < 1024) ? bq[i] * 0.125f : (i < 2048) ? bk[i - 1024] : bv[i - 2048];
}

// src [K][N] fp32 -> dst [N][K] bf16 (B^T layout), K = 1<<kshift
__global__ void k_transpose(const float* __restrict__ src, unsigned short* __restrict__ dst,
                            int kshift, int N){
  int i = blockIdx.x * 256 + threadIdx.x;   // over N*K
  int K = 1 << kshift;
  int k = i & (K - 1);
  int n = i >> kshift;
  dst[i] = f2bf(src[(size_t)k * N + n]);
}

// ---------------- bf16 MFMA GEMM, 128x128 tile + global_load_lds (m97 structure) ----------------
template<int RELU, int OUTBF>
__global__ void __launch_bounds__(256) k_gemm128(const unsigned short* __restrict__ A,
                                                 const unsigned short* __restrict__ Bt,
                                                 const float* __restrict__ bias,
                                                 void* __restrict__ Cout, int N, int K){
  __shared__ unsigned short As[128 * 32];
  __shared__ unsigned short Bs[128 * 32];
  const int t = threadIdx.x;
  const int m0 = blockIdx.y << 7, n0 = blockIdx.x << 7;
  const int lane = t & 63, w = t >> 6;
  const int quad = lane >> 4, l16 = lane & 15;
  const int mw = (w & 1) << 6, nw = (w >> 1) << 6;
  floatx4 acc[4][4];
  #pragma unroll
  for (int i = 0; i < 4; i++)
    #pragma unroll
    for (int j = 0; j < 4; j++) acc[i][j] = (floatx4){0.f, 0.f, 0.f, 0.f};
  const unsigned short* Ag  = A  + (size_t)(m0 + (t >> 2)) * K + ((t & 3) << 3);
  const unsigned short* Ag2 = Ag + (size_t)64 * K;
  const unsigned short* Bg  = Bt + (size_t)(n0 + (t >> 2)) * K + ((t & 3) << 3);
  const unsigned short* Bg2 = Bg + (size_t)64 * K;
  for (int kb = 0; kb < K; kb += 32){
    __builtin_amdgcn_global_load_lds((g_uint*)(Ag  + kb), (lds_uint*)&As[t << 3],          16, 0, 0);
    __builtin_amdgcn_global_load_lds((g_uint*)(Ag2 + kb), (lds_uint*)&As[2048 + (t << 3)], 16, 0, 0);
    __builtin_amdgcn_global_load_lds((g_uint*)(Bg  + kb), (lds_uint*)&Bs[t << 3],          16, 0, 0);
    __builtin_amdgcn_global_load_lds((g_uint*)(Bg2 + kb), (lds_uint*)&Bs[2048 + (t << 3)], 16, 0, 0);
    __syncthreads();
    bf16x8 af[4], bf[4];
    #pragma unroll
    for (int mt = 0; mt < 4; mt++)
      af[mt] = *(const bf16x8*)&As[((mw + (mt << 4) + l16) << 5) + (quad << 3)];
    #pragma unroll
    for (int nt = 0; nt < 4; nt++)
      bf[nt] = *(const bf16x8*)&Bs[((nw + (nt << 4) + l16) << 5) + (quad << 3)];
    #pragma unroll
    for (int mt = 0; mt < 4; mt++)
      #pragma unroll
      for (int nt = 0; nt < 4; nt++)
        acc[mt][nt] = __builtin_amdgcn_mfma_f32_16x16x32_bf16(af[mt], bf[nt], acc[mt][nt], 0, 0, 0);
    __syncthreads();
  }
  #pragma unroll
  for (int nt = 0; nt < 4; nt++){
    const int col = n0 + nw + (nt << 4) + l16;
    const float bsv = bias[col];
    #pragma unroll
    for (int mt = 0; mt < 4; mt++){
      const int row = m0 + mw + (mt << 4) + (quad << 2);
      #pragma unroll
      for (int r = 0; r < 4; r++){
        float v = acc[mt][nt][r] + bsv;
        if (RELU) v = fmaxf(v, 0.f);
        if (OUTBF) ((unsigned short*)Cout)[(size_t)(row + r) * N + col] = f2bf(v);
        else       ((float*)Cout)[(size_t)(row + r) * N + col] = v;
      }
    }
  }
}

// ---------------- MFMA flash attention (R3 structure, LDS-compacted) ----------------
// PQs (9.2 KB) serves three roles, time-multiplexed with barriers between:
//   (1) pre-loop Q staging [64 q][72 d] (dead after frag load);
//   (2) per-wave S round-trip (bf16): wave w owns rows w*16..w*16+15;
//   (3) per-wave P storage for the PV B-fragment (same rows).
// All softmax LDS traffic is wave-private. LDS total ~28 KB -> 5 blocks/CU.
__global__ void __launch_bounds__(256) k_attn(const unsigned short* __restrict__ qkvb,
                                              const int* __restrict__ amask,
                                              unsigned short* __restrict__ ctxb){
  __shared__ __align__(16) unsigned short Ks[64 * 72];   // [key][d]
  __shared__ __align__(16) unsigned short Vt[64 * 72];   // [d][key]
  __shared__ __align__(16) unsigned short PQs[64 * 72];  // Q stage / S / P (see above)
  __shared__ int msk[64];
  const int t = threadIdx.x;
  const int w = t >> 6, lane = t & 63;
  const int quad = lane >> 4, l16 = lane & 15;
  const int b = blockIdx.y >> 4, h = blockIdx.y & 15;
  const int q0 = blockIdx.x << 6;
  const int sr = t >> 2, sc = (t & 3) << 4;        // Q/K staging: row, 16-short chunk
  const int kg = t >> 4, dc = (t & 15) << 2;       // V staging: 4-key group, 4-d chunk
  const int myrow = (w << 4) + l16;                // this lane's private PQs row (q = l16 within wave)

  // ---- stage Q tile into PQs, load A-frags, then PQs is free for S/P ----
  {
    const unsigned short* qs = qkvb + (size_t)((b << 11) + q0 + sr) * 3072 + (h << 6) + sc;
    *(uint4*)&PQs[sr * 72 + sc]     = *(const uint4*)qs;
    *(uint4*)&PQs[sr * 72 + sc + 8] = *(const uint4*)(qs + 8);
  }
  __syncthreads();
  const bf16x8 qf0 = *(const bf16x8*)&PQs[myrow * 72 + (quad << 3)];
  const bf16x8 qf1 = *(const bf16x8*)&PQs[myrow * 72 + (quad << 3) + 32];

  floatx4 accO[4];
  #pragma unroll
  for (int i = 0; i < 4; i++) accO[i] = (floatx4){0.f, 0.f, 0.f, 0.f};
  float m_run = -3.0e38f, l_run = 0.f;             // for q = l16 (replicated over the 4 quads)

  const unsigned short* kbase = qkvb + (size_t)((b << 11) + sr) * 3072 + 1024 + (h << 6) + sc;
  const unsigned short* vbase = qkvb + (size_t)((b << 11) + (kg << 2)) * 3072 + 2048 + (h << 6) + dc;
  const int* mbase = amask + (b << 11);

  for (int k0 = 0; k0 < SEQ; k0 += 64){
    __syncthreads();                               // prev iteration's K/V readers done (Q-frag read on iter 0)
    {
      const unsigned short* ks = kbase + (size_t)k0 * 3072;
      *(uint4*)&Ks[sr * 72 + sc]     = *(const uint4*)ks;
      *(uint4*)&Ks[sr * 72 + sc + 8] = *(const uint4*)(ks + 8);
    }
    {
      const unsigned short* vs = vbase + (size_t)k0 * 3072;
      ushort4 r0 = *(const ushort4*)(vs);
      ushort4 r1 = *(const ushort4*)(vs + 3072);
      ushort4 r2 = *(const ushort4*)(vs + 2 * 3072);
      ushort4 r3 = *(const ushort4*)(vs + 3 * 3072);
      ushort4 c;
      c.x = r0.x; c.y = r1.x; c.z = r2.x; c.w = r3.x; *(ushort4*)&Vt[(dc + 0) * 72 + (kg << 2)] = c;
      c.x = r0.y; c.y = r1.y; c.z = r2.y; c.w = r3.y; *(ushort4*)&Vt[(dc + 1) * 72 + (kg << 2)] = c;
      c.x = r0.z; c.y = r1.z; c.z = r2.z; c.w = r3.z; *(ushort4*)&Vt[(dc + 2) * 72 + (kg << 2)] = c;
      c.x = r0.w; c.y = r1.w; c.z = r2.w; c.w = r3.w; *(ushort4*)&Vt[(dc + 3) * 72 + (kg << 2)] = c;
    }
    if (t < 64) msk[t] = mbase[k0 + t];
    __syncthreads();

    // ---- QK^T: S[16q][64key] per wave ----
    floatx4 sc4[4];
    #pragma unroll
    for (int ns = 0; ns < 4; ns++){
      sc4[ns] = (floatx4){0.f, 0.f, 0.f, 0.f};
      const unsigned short* kp = &Ks[((ns << 4) + l16) * 72 + (quad << 3)];
      bf16x8 kf0 = *(const bf16x8*)(kp);
      bf16x8 kf1 = *(const bf16x8*)(kp + 32);
      sc4[ns] = __builtin_amdgcn_mfma_f32_16x16x32_bf16(qf0, kf0, sc4[ns], 0, 0, 0);
      sc4[ns] = __builtin_amdgcn_mfma_f32_16x16x32_bf16(qf1, kf1, sc4[ns], 0, 0, 0);
    }
    // ---- S -> PQs as bf16 (C-layout write: q = quad*4+r, key = ns*16+l16) ----
    #pragma unroll
    for (int ns = 0; ns < 4; ns++)
      #pragma unroll
      for (int r = 0; r < 4; r++)
        PQs[((w << 4) + (quad << 2) + r) * 72 + (ns << 4) + l16] = f2bf_tr(sc4[ns][r]);
    __syncthreads();

    // ---- re-read in q=l16 layout: lane owns row myrow, keys quad*16..+15 (32B = 2x b128) ----
    float sv[16];
    {
      const uint4 s0 = *(const uint4*)&PQs[myrow * 72 + (quad << 4)];
      const uint4 s1 = *(const uint4*)&PQs[myrow * 72 + (quad << 4) + 8];
      const unsigned u[8] = {s0.x, s0.y, s0.z, s0.w, s1.x, s1.y, s1.z, s1.w};
      #pragma unroll
      for (int j = 0; j < 8; j++){
        union { unsigned u; float f; } lo, hi;
        lo.u = u[j] << 16; hi.u = u[j] & 0xffff0000u;
        sv[2 * j] = lo.f; sv[2 * j + 1] = hi.f;
      }
    }
    #pragma unroll
    for (int e = 0; e < 16; e++)
      if (msk[(quad << 4) + e] == 0) sv[e] = NEGV;
    float tmax = sv[0];
    #pragma unroll
    for (int e = 1; e < 16; e++) tmax = fmaxf(tmax, sv[e]);
    tmax = fmaxf(tmax, __shfl_xor(tmax, 16));
    tmax = fmaxf(tmax, __shfl_xor(tmax, 32));
    const float mnew = fmaxf(m_run, tmax);
    const float alpha = __expf(m_run - mnew);
    float pv[16], lsum = 0.f;
    #pragma unroll
    for (int e = 0; e < 16; e++){ pv[e] = __expf(sv[e] - mnew); lsum += pv[e]; }
    lsum += __shfl_xor(lsum, 16);
    lsum += __shfl_xor(lsum, 32);
    l_run = l_run * alpha + lsum;
    m_run = mnew;
    // ---- P -> PQs (same addresses this lane just read; packed 2x b128) ----
    {
      unsigned pk[8];
      #pragma unroll
      for (int j = 0; j < 8; j++){
        union { float f; unsigned u; } a, c;
        a.f = pv[2 * j]; c.f = pv[2 * j + 1];
        pk[j] = (a.u >> 16) | (c.u & 0xffff0000u);
      }
      uint4 w0 = {pk[0], pk[1], pk[2], pk[3]};
      uint4 w1 = {pk[4], pk[5], pk[6], pk[7]};
      *(uint4*)&PQs[myrow * 72 + (quad << 4)]     = w0;
      *(uint4*)&PQs[myrow * 72 + (quad << 4) + 8] = w1;
    }
    __syncthreads();

    // ---- O^T[d][q] += V^T[d][k] P^T[k][q]; rescale accO by alpha (both indexed q=l16) ----
    const bf16x8 pf0 = *(const bf16x8*)&PQs[myrow * 72 + (quad << 3)];
    const bf16x8 pf1 = *(const bf16x8*)&PQs[myrow * 72 + (quad << 3) + 32];
    #pragma unroll
    for (int mt = 0; mt < 4; mt++){
      #pragma unroll
      for (int i = 0; i < 4; i++) accO[mt][i] *= alpha;
      const unsigned short* vp = &Vt[((mt << 4) + l16) * 72 + (quad << 3)];
      bf16x8 vf0 = *(const bf16x8*)(vp);
      bf16x8 vf1 = *(const bf16x8*)(vp + 32);
      accO[mt] = __builtin_amdgcn_mfma_f32_16x16x32_bf16(vf0, pf0, accO[mt], 0, 0, 0);
      accO[mt] = __builtin_amdgcn_mfma_f32_16x16x32_bf16(vf1, pf1, accO[mt], 0, 0, 0);
    }
  }
  // ---- epilogue: O[q][d] = accO / l_run; q = l16 (col), d = mt*16 + quad*4 + reg (row) ----
  const float linv = 1.f / l_run;
  unsigned short* orow = ctxb + (size_t)((b << 11) + q0 + myrow) * 1024 + (h << 6);
  #pragma unroll
  for (int mt = 0; mt < 4; mt++){
    ushort4 o;
    o.x = f2bf(accO[mt][0] * linv);
    o.y = f2bf(accO[mt][1] * linv);
    o.z = f2bf(accO[mt][2] * linv);
    o.w = f2bf(accO[mt][3] * linv);
    *(ushort4*)&orow[(mt << 4) + (quad << 2)] = o;
  }
}

// ---------------- residual + LayerNorm (1024 cols, one block per row) ----------------
__global__ void __launch_bounds__(256) k_ln(const float* __restrict__ a, const float* __restrict__ res,
                                            const float* __restrict__ gg, const float* __restrict__ bb,
                                            float* __restrict__ out, unsigned short* __restrict__ outb){
  const int row = blockIdx.x, t = threadIdx.x;
  const float4 av = ((const float4*)(a   + (size_t)row * 1024))[t];
  const float4 rv = ((const float4*)(res + (size_t)row * 1024))[t];
  float4 v; v.x = av.x + rv.x; v.y = av.y + rv.y; v.z = av.z + rv.z; v.w = av.w + rv.w;
  float sum = v.x + v.y + v.z + v.w;
  float ss  = v.x * v.x + v.y * v.y + v.z * v.z + v.w * v.w;
  #pragma unroll
  for (int off = 32; off > 0; off >>= 1){
    sum += __shfl_down(sum, off);
    ss  += __shfl_down(ss, off);
  }
  __shared__ float red[8];
  const int w = t >> 6;
  if ((t & 63) == 0){ red[w] = sum; red[4 + w] = ss; }
  __syncthreads();
  const float S  = red[0] + red[1] + red[2] + red[3];
  const float SS = red[4] + red[5] + red[6] + red[7];
  const float mu  = S * (1.f / 1024.f);
  const float var = SS * (1.f / 1024.f) - mu * mu;
  const float rs  = rsqrtf(var + 1e-5f);
  const float4 gv = ((const float4*)gg)[t];
  const float4 bv = ((const float4*)bb)[t];
  float4 o;
  o.x = (v.x - mu) * rs * gv.x + bv.x;
  o.y = (v.y - mu) * rs * gv.y + bv.y;
  o.z = (v.z - mu) * rs * gv.z + bv.z;
  o.w = (v.w - mu) * rs * gv.w + bv.w;
  ((float4*)(out + (size_t)row * 1024))[t] = o;
  if (outb){
    ushort4 ob; ob.x = f2bf(o.x); ob.y = f2bf(o.y); ob.z = f2bf(o.z); ob.w = f2bf(o.w);
    ((ushort4*)(outb + (size_t)row * 1024))[t] = ob;
  }
}

extern "C" void kernel_launch(void* const* d_in, const int* in_sizes, int n_in,
                              void* d_out, int out_size, void* d_ws, size_t ws_size,
                              hipStream_t stream){
  const float* x     = (const float*)d_in[0];
  const int*   amask = (const int*)d_in[1];
  const float* Wq    = (const float*)d_in[2];
  const float* bq    = (const float*)d_in[3];
  const float* Wk    = (const float*)d_in[4];
  const float* bk    = (const float*)d_in[5];
  const float* Wv    = (const float*)d_in[6];
  const float* bv    = (const float*)d_in[7];
  const float* Wo    = (const float*)d_in[8];
  const float* bo    = (const float*)d_in[9];
  const float* g1    = (const float*)d_in[10];
  const float* b1    = (const float*)d_in[11];
  const float* W1    = (const float*)d_in[12];
  const float* bias1 = (const float*)d_in[13];
  const float* W2    = (const float*)d_in[14];
  const float* bias2 = (const float*)d_in[15];
  const float* g2    = (const float*)d_in[16];
  const float* b2    = (const float*)d_in[17];

  char* ws = (char*)d_ws;
  unsigned short* xb    = (unsigned short*)(ws + 0);            //  8 MB
  unsigned short* wqkvt = (unsigned short*)(ws + 8388608);      //  6 MB
  float*          qbias = (float*)         (ws + 14680064);     // 12 KB
  unsigned short* wot   = (unsigned short*)(ws + 14692352);     //  2 MB
  unsigned short* w1t   = (unsigned short*)(ws + 16789504);     //  4 MB
  unsigned short* w2t   = (unsigned short*)(ws + 20983808);     //  4 MB
  unsigned short* ctxb  = (unsigned short*)(ws + 25178112);     //  8 MB
  float*          attn  = (float*)         (ws + 33566720);     // 16 MB (also FFN out)
  float*          fbuf  = attn;
  unsigned short* qkvb  = (unsigned short*)(ws + 50343936);     // 24 MB: QKV bf16 [4096][3072]
  float*          out1  = (float*)         (ws + 50343936);     // reuse (qkvb dead after attn)
  unsigned short* out1b = (unsigned short*)(ws + 50343936 + 25165824);  // 8 MB
  unsigned short* h1    = (unsigned short*)(ws + 50343936 + 33554432);  // 16 MB

  // --- prep ---
  k_cvt_bf16   <<<dim3(4096),  dim3(256), 0, stream>>>(x, xb);
  k_build_wqkvt<<<dim3(12288), dim3(256), 0, stream>>>(Wq, Wk, Wv, wqkvt);
  k_build_qbias<<<dim3(12),    dim3(256), 0, stream>>>(bq, bk, bv, qbias);
  k_transpose  <<<dim3(4096),  dim3(256), 0, stream>>>(Wo, wot, 10, MDIM);
  k_transpose  <<<dim3(8192),  dim3(256), 0, stream>>>(W1, w1t, 10, FFH);
  k_transpose  <<<dim3(8192),  dim3(256), 0, stream>>>(W2, w2t, 11, MDIM);

  // --- QKV projection -> bf16 (Q pre-scaled by 1/8 via Wq/bq) ---
  k_gemm128<0,1><<<dim3(24, 32), dim3(256), 0, stream>>>(xb, wqkvt, qbias, qkvb, 3072, 1024);
  // --- MFMA flash attention -> ctxb bf16 ---
  k_attn<<<dim3(32, 32), dim3(256), 0, stream>>>(qkvb, amask, ctxb);
  // --- output projection ---
  k_gemm128<0,0><<<dim3(8, 32), dim3(256), 0, stream>>>(ctxb, wot, bo, attn, MDIM, 1024);
  // --- LN1(attn + x) ---
  k_ln<<<dim3(4096), dim3(256), 0, stream>>>(attn, x, g1, b1, out1, out1b);
  // --- FFN ---
  k_gemm128<1,1><<<dim3(16, 32), dim3(256), 0, stream>>>(out1b, w1t, bias1, h1, FFH, 1024);
  k_gemm128<0,0><<<dim3(8, 32), dim3(256), 0, stream>>>(h1, w2t, bias2, fbuf, MDIM, 2048);
  // --- LN2(out1 + f) -> d_out ---
  k_ln<<<dim3(4096), dim3(256), 0, stream>>>(fbuf, out1, g2, b2, (float*)d_out, nullptr);
}